// Round 3
// baseline (1603.826 us; speedup 1.0000x reference)
//
#include <hip/hip_runtime.h>

#define S_LEN 1024
#define BATCH 128

using u16 = unsigned short;
using u32 = unsigned int;
typedef _Float16 f16;
typedef __attribute__((ext_vector_type(2))) _Float16 f16x2;
typedef __attribute__((ext_vector_type(8))) _Float16 f16x8;
typedef __attribute__((ext_vector_type(4))) float floatx4;

__device__ __forceinline__ float fexp(float x) {
    return __builtin_amdgcn_exp2f(x * 1.4426950408889634f);
}
__device__ __forceinline__ float fsigmoid(float x) {
    return __builtin_amdgcn_rcpf(1.f + fexp(-x));
}
__device__ __forceinline__ float ftanh(float x) {
    return 1.f - 2.f * __builtin_amdgcn_rcpf(fexp(2.f * x) + 1.f);
}

// ---------------- prep: fp32 weights -> f16, bias sums ----------------
__global__ __launch_bounds__(256) void prep_kernel(
        const float* __restrict__ Wih0, const float* __restrict__ Whh0f,
        const float* __restrict__ Wih1, const float* __restrict__ Whh1f,
        const float* __restrict__ bih0, const float* __restrict__ bhh0,
        const float* __restrict__ bih1, const float* __restrict__ bhh1,
        f16* __restrict__ W0, f16* __restrict__ W1,
        f16* __restrict__ Wh0, f16* __restrict__ Wh1,
        float* __restrict__ b0, float* __restrict__ b1) {
    int i = blockIdx.x * 256 + threadIdx.x;
    if (i < 131072) {               // 2*512*128
        W0[i]  = (f16)Wih0[i];
        Wh0[i] = (f16)Whh0f[i];
        Wh1[i] = (f16)Whh1f[i];
    }
    if (i < 262144) W1[i] = (f16)Wih1[i];   // 2*512*256
    if (i < 1024) { b0[i] = bih0[i] + bhh0[i]; b1[i] = bih1[i] + bhh1[i]; }
}

// ---------------- chunked projection GEMM ----------------
// Computes xgc[dir][l][0..511] = A_row(sidx,b) @ W[dir*512+?]^T + bias for one S-chunk,
// both directions. l = ls*128+b; sidx = dir ? s0b-ls : s0+ls.
// GATHER=true: A_row = f16(emb[inputs[b][sidx]])  (fused embedding, layer 0, K=128)
// GATHER=false: A_row = hs0[sidx*128+b]           (layer 1, K=256)
template<int K, bool GATHER>
__global__ __launch_bounds__(256) void proj_chunk(
        const f16* __restrict__ A, const int* __restrict__ inputs,
        const float* __restrict__ emb, const f16* __restrict__ Bw,
        const float* __restrict__ bias, f16* __restrict__ C,
        int s0, int s0b, int CH) {
    __shared__ __align__(16) f16 As[128][72];   // +8 pad, 144B row stride
    __shared__ __align__(16) f16 Bs[128][72];
    const int t = threadIdx.x;
    // T1 bijective XCD remap (nwg = 8*CH, %8==0)
    const u32 nwg8 = gridDim.x >> 3;
    const u32 bid = (blockIdx.x & 7) * nwg8 + (blockIdx.x >> 3);
    const u32 per_dir = (u32)CH * 4;
    const int dir = (int)(bid / per_dir);
    const u32 rr = bid % per_dir;
    const int mt = (int)(rr >> 2);
    const int n0 = (int)(rr & 3) * 128;
    const int lane = t & 63, wid = t >> 6;
    const int wm = wid >> 1, wn = wid & 1;
    const int lrow = lane & 15;
    const int lk8  = (lane >> 4) * 8;

    floatx4 acc[4][4] = {};

    const int srow = t >> 3;        // 0..31
    const int scol = (t & 7) * 8;   // 0..56
    for (int k0 = 0; k0 < K; k0 += 64) {
        __syncthreads();
        #pragma unroll
        for (int r = 0; r < 4; ++r) {
            int row = srow + r * 32;
            int l = mt * 128 + row;
            int bb = l & 127, ls = l >> 7;
            int sidx = dir ? (s0b - ls) : (s0 + ls);
            if constexpr (GATHER) {
                int idx = inputs[bb * S_LEN + sidx];
                const float* ep = emb + (size_t)idx * 128 + k0 + scol;
                float4 v0 = *reinterpret_cast<const float4*>(ep);
                float4 v1 = *reinterpret_cast<const float4*>(ep + 4);
                f16x8 o = { (f16)v0.x, (f16)v0.y, (f16)v0.z, (f16)v0.w,
                            (f16)v1.x, (f16)v1.y, (f16)v1.z, (f16)v1.w };
                *reinterpret_cast<f16x8*>(&As[row][scol]) = o;
            } else {
                uint4 av = *reinterpret_cast<const uint4*>(
                    A + (size_t)(sidx * 128 + bb) * K + k0 + scol);
                *reinterpret_cast<uint4*>(&As[row][scol]) = av;
            }
            uint4 bv = *reinterpret_cast<const uint4*>(
                Bw + (size_t)(dir * 512 + n0 + row) * K + k0 + scol);
            *reinterpret_cast<uint4*>(&Bs[row][scol]) = bv;
        }
        __syncthreads();
        #pragma unroll
        for (int ks = 0; ks < 2; ++ks) {
            f16x8 af[4], bf[4];
            #pragma unroll
            for (int f = 0; f < 4; ++f) {
                af[f] = *reinterpret_cast<const f16x8*>(&As[wm * 64 + f * 16 + lrow][ks * 32 + lk8]);
                bf[f] = *reinterpret_cast<const f16x8*>(&Bs[wn * 64 + f * 16 + lrow][ks * 32 + lk8]);
            }
            #pragma unroll
            for (int fm = 0; fm < 4; ++fm)
                #pragma unroll
                for (int fn = 0; fn < 4; ++fn)
                    acc[fm][fn] = __builtin_amdgcn_mfma_f32_16x16x32_f16(
                        af[fm], bf[fn], acc[fm][fn], 0, 0, 0);
        }
    }
    // epilogue: C/D layout col=lane&15, row=(lane>>4)*4+reg  [m89, dtype-independent]
    f16* Cd = C + (size_t)dir * CH * 128 * 512;
    #pragma unroll
    for (int fn = 0; fn < 4; ++fn) {
        int col = n0 + wn * 64 + fn * 16 + lrow;          // 0..511 within dir
        float bv = bias[dir * 512 + col];
        #pragma unroll
        for (int fm = 0; fm < 4; ++fm) {
            int rowl = mt * 128 + wm * 64 + fm * 16 + (lane >> 4) * 4;
            #pragma unroll
            for (int r = 0; r < 4; ++r) {
                float v = acc[fm][fn][r] + bv;
                Cd[(size_t)(rowl + r) * 512 + col] = (f16)v;
            }
        }
    }
}

// ---------------- LSTM recurrence (one S-chunk) ----------------
// One WG per (dir, batch-row): 256 WGs = 1/CU. 512 threads; thread t owns gate row j=t,
// Whh row as 64 f16x2 VGPRs (v_pk_fma_f16 -> 256cy/step issue floor). h broadcast via LDS.
// Raw barriers (lgkmcnt-only) keep the xg prefetch in flight. (h,c) carried in ws.
template<int LAYER>
__global__ __launch_bounds__(512, 2) void recur_chunk(
        const f16* __restrict__ xgc,    // [2][CH*128][512]
        const f16* __restrict__ Whh,    // [1024][128] f16
        f16* __restrict__ hs_out,       // LAYER 0: [S*B][256]
        float* __restrict__ h_state,    // [2*128][128]
        float* __restrict__ c_state,    // [2*128][128]
        int s0, int s0b, int CH, int first) {
    const int t = threadIdx.x;
    const int dir = blockIdx.x >> 7;
    const int b = blockIdx.x & 127;

    __shared__ __align__(16) f16 h16[128];
    __shared__ float act_lds[512];

    f16x2 w2[64];
    {
        const f16x8* wp8 = reinterpret_cast<const f16x8*>(Whh + (size_t)(dir * 512 + t) * 128);
        #pragma unroll
        for (int k = 0; k < 16; ++k) {
            f16x8 v = wp8[k];
            w2[4*k+0] = f16x2{v[0], v[1]};
            w2[4*k+1] = f16x2{v[2], v[3]};
            w2[4*k+2] = f16x2{v[4], v[5]};
            w2[4*k+3] = f16x2{v[6], v[7]};
        }
    }

    const int sbase = (dir * 128 + b) * 128 + t;   // t<128 only
    float c = 0.f;
    if (t < 128) {
        if (first) { h16[t] = (f16)0.f; }
        else       { h16[t] = (f16)h_state[sbase]; c = c_state[sbase]; }
    }
    __syncthreads();

    const f16* xbase = xgc + ((size_t)(dir * CH) * 128 + b) * 512 + t;
    auto xaddr = [&](int li) -> const f16* {
        return xbase + (size_t)li * (128 * 512);
    };

    const f16x8* hp = reinterpret_cast<const f16x8*>(h16);

    auto step = [&](int li, f16 xv) {
        f16x2 acc0{}, acc1{}, acc2{}, acc3{};
        #pragma unroll
        for (int k = 0; k < 16; ++k) {
            f16x8 hv = hp[k];                    // uniform-address broadcast b128
            acc0 += f16x2{hv[0], hv[1]} * w2[4*k+0];
            acc1 += f16x2{hv[2], hv[3]} * w2[4*k+1];
            acc2 += f16x2{hv[4], hv[5]} * w2[4*k+2];
            acc3 += f16x2{hv[6], hv[7]} * w2[4*k+3];
        }
        f16x2 s0v = acc0 + acc1, s1v = acc2 + acc3, sv = s0v + s1v;
        float g = (float)xv + (float)sv[0] + (float)sv[1];
        // gate groups (wave-uniform): 0=i(sig) 1=f(sig) 2=g(tanh) 3=o(sig) -- PyTorch order
        float a = ((t >> 7) == 2) ? ftanh(g) : fsigmoid(g);
        act_lds[t] = a;
        asm volatile("s_waitcnt lgkmcnt(0)" ::: "memory");
        __builtin_amdgcn_s_barrier();
        asm volatile("" ::: "memory");
        if (t < 128) {
            float ai = act_lds[t], af = act_lds[t + 128];
            float ag = act_lds[t + 256], ao = act_lds[t + 384];
            c = af * c + ai * ag;
            float hn = ao * ftanh(c);
            h16[t] = (f16)hn;
            if (LAYER == 0) {
                int sidx = dir ? (s0b - li) : (s0 + li);
                hs_out[(size_t)(sidx * BATCH + b) * 256 + dir * 128 + t] = (f16)hn;
            }
        }
        asm volatile("s_waitcnt lgkmcnt(0)" ::: "memory");
        __builtin_amdgcn_s_barrier();
        asm volatile("" ::: "memory");
    };

    // depth-2 prefetch, unrolled by 2 (static rotation by naming)
    f16 xa = *xaddr(0);
    f16 xb_ = *xaddr(CH > 1 ? 1 : 0);
    for (int li = 0; li < CH; li += 2) {
        f16 xc = *xaddr(li + 2 < CH ? li + 2 : CH - 1);
        step(li, xa);
        f16 xd = *xaddr(li + 3 < CH ? li + 3 : CH - 1);
        step(li + 1, xb_);
        xa = xc; xb_ = xd;
    }
    if (t < 128) {
        h_state[sbase] = (float)h16[t];
        c_state[sbase] = c;
    }
}

// ---------------- decoder ----------------
__global__ __launch_bounds__(64) void decode_kernel(
        const float* __restrict__ h_state, const float* __restrict__ decW,
        const float* __restrict__ decb, const float* __restrict__ fc1W,
        const float* __restrict__ fc1b, float* __restrict__ out) {
    __shared__ float t1[64];
    int b = blockIdx.x, j = threadIdx.x;
    float acc = decb[j];
    const float* h0 = h_state + (size_t)b * 128;           // dir0
    const float* h1 = h_state + (size_t)(128 + b) * 128;   // dir1
    const float* wr = decW + (size_t)j * 256;
    #pragma unroll 4
    for (int k = 0; k < 128; ++k) acc += h0[k] * wr[k];
    #pragma unroll 4
    for (int k = 0; k < 128; ++k) acc += h1[k] * wr[128 + k];
    t1[j] = acc;
    __syncthreads();
    if (j < 2) {
        float o = fc1b[j];
        #pragma unroll
        for (int k = 0; k < 64; ++k) o += t1[k] * fc1W[j * 64 + k];
        out[b * 2 + j] = o;
    }
}

extern "C" void kernel_launch(void* const* d_in, const int* in_sizes, int n_in,
                              void* d_out, int out_size, void* d_ws, size_t ws_size,
                              hipStream_t stream) {
    const int*   inputs = (const int*)d_in[0];
    const float* emb    = (const float*)d_in[1];
    const float* Wih0   = (const float*)d_in[2];
    const float* Whh0   = (const float*)d_in[3];
    const float* bih0   = (const float*)d_in[4];
    const float* bhh0   = (const float*)d_in[5];
    const float* Wih1   = (const float*)d_in[6];
    const float* Whh1   = (const float*)d_in[7];
    const float* bih1   = (const float*)d_in[8];
    const float* bhh1   = (const float*)d_in[9];
    const float* decW   = (const float*)d_in[10];
    const float* decb   = (const float*)d_in[11];
    const float* fc1W   = (const float*)d_in[12];
    const float* fc1b   = (const float*)d_in[13];
    float* out = (float*)d_out;

    char* ws = (char*)d_ws;
    size_t off = 0;
    auto alloc = [&](size_t bytes) {
        char* p = ws + off;
        off = (off + bytes + 255) & ~(size_t)255;
        return p;
    };
    f16*   W0      = (f16*)alloc((size_t)131072 * 2);
    f16*   W1      = (f16*)alloc((size_t)262144 * 2);
    f16*   Wh0     = (f16*)alloc((size_t)131072 * 2);
    f16*   Wh1     = (f16*)alloc((size_t)131072 * 2);
    float* b0      = (float*)alloc(1024 * 4);
    float* b1      = (float*)alloc(1024 * 4);
    float* h_state = (float*)alloc((size_t)2 * 128 * 128 * 4);
    float* c_state = (float*)alloc((size_t)2 * 128 * 128 * 4);
    f16*   hs0     = (f16*)alloc((size_t)131072 * 256 * 2);   // 64 MiB
    size_t fixed_end = off;

    // pick the largest S-chunk whose xg buffer fits the remaining workspace
    int CH = 32;
    size_t avail = (ws_size > fixed_end) ? (ws_size - fixed_end) : 0;
    for (int c = 1024; c >= 32; c >>= 1) {
        if ((size_t)c * 262144 <= avail) { CH = c; break; }
    }
    f16* xgc = (f16*)alloc((size_t)CH * 262144);   // [2][CH*128][512] f16
    const int NC = S_LEN / CH;

    prep_kernel<<<1024, 256, 0, stream>>>(Wih0, Whh0, Wih1, Whh1,
                                          bih0, bhh0, bih1, bhh1,
                                          W0, W1, Wh0, Wh1, b0, b1);
    for (int ci = 0; ci < NC; ++ci) {
        int s0 = ci * CH, s0b = S_LEN - 1 - ci * CH;
        proj_chunk<128, true><<<8 * CH, 256, 0, stream>>>(
            nullptr, inputs, emb, W0, b0, xgc, s0, s0b, CH);
        recur_chunk<0><<<256, 512, 0, stream>>>(
            xgc, Wh0, hs0, h_state, c_state, s0, s0b, CH, ci == 0);
    }
    for (int ci = 0; ci < NC; ++ci) {
        int s0 = ci * CH, s0b = S_LEN - 1 - ci * CH;
        proj_chunk<256, false><<<8 * CH, 256, 0, stream>>>(
            hs0, nullptr, nullptr, W1, b1, xgc, s0, s0b, CH);
        recur_chunk<1><<<256, 512, 0, stream>>>(
            xgc, Wh1, nullptr, h_state, c_state, s0, s0b, CH, ci == 0);
    }
    decode_kernel<<<128, 64, 0, stream>>>(h_state, decW, decb, fc1W, fc1b, out);
}